// Round 2
// baseline (213.256 us; speedup 1.0000x reference)
//
#include <hip/hip_runtime.h>

// Batched autocorrelation, X:[4096,8192] f32 -> out:[4096,64] f32.
// Per-row correlation as bf16 MFMA Gram matrices:
//   X_i[m] = x[32 i + m];  G_d[m][n] = sum_i X_i[m] * X_{i+d}[n], d=0..2
//   R_{32q+s} = sum_{m+s<32} G_q[m][m+s] + sum_{m+s>=32} G_{q+1}[m][m+s-32]
// Centering folded in algebraically (fp32):
//   C_k = R_k - mu*(2S - P_k - Q_k) + (T-k) mu^2 ;  out = C_k / C_0
//
// R4: latency-theory discriminator. Depth-2 register pipeline:
//   * batch c's 10 loads are issued TWO iterations before their compute ->
//     ~20-30 dwords in flight/wave, wait-distance ~2 full iterations.
//   * e8/e9 revert to direct loads (L2 hits, proven free in R3) so compute(c)
//     depends ONLY on batch c -- no cross-iteration shuffle, no ds_bpermute
//     on the critical path.
//   * cvt_pk_bf16_f32 (1 instr, RNE; bit-matched software pack in R3).
// LDS is only a 6.5 KB/wave bf16 G-dump for the diagonal-band reduction.
// Occupancy: 256 thr/block, <=128 VGPR -> 4 blocks/CU = 16 waves/CU.

typedef __bf16 bf16x8 __attribute__((ext_vector_type(8)));
typedef float f32x16 __attribute__((ext_vector_type(16)));
typedef unsigned int uint32;

#define T_LEN 8192
#define WPB 4                       // waves (rows) per block
#define GB_STRIDE 34                // shorts per G row (+2 pad)
#define GB_SHORTS (96 * GB_STRIDE)  // 3 matrices x 32 rows = 6528 B / wave

__device__ __forceinline__ uint32 cvtpk(float lo, float hi) { // (lo, hi) RNE
  uint32 r;
  asm("v_cvt_pk_bf16_f32 %0, %1, %2" : "=v"(r) : "v"(lo), "v"(hi));
  return r;
}
__device__ __forceinline__ short f2bf(float f) {
  uint32 u = __builtin_bit_cast(uint32, f);
  return (short)((u + 0x7fffu + ((u >> 16) & 1u)) >> 16);
}
__device__ __forceinline__ float bf2f(short h) {
  uint32 u = ((uint32)(unsigned short)h) << 16;
  return __builtin_bit_cast(float, u);
}

// ---- 10-element batch macros (named regs only: rule #20, no runtime indexing)
#define DECL10(V) float V##0, V##1, V##2, V##3, V##4, V##5, V##6, V##7, V##8, V##9;

// full batch: e8/e9 (p[256],p[288]) duplicate neighboring data -> L1/L2 hits,
// but keep compute(c) dependent only on batch c.
#define LOAD10(V, c) {                                                          \
    const float* p = base + ((c) << 9);                                         \
    V##0 = p[0];   V##1 = p[32];  V##2 = p[64];  V##3 = p[96];                  \
    V##4 = p[128]; V##5 = p[160]; V##6 = p[192]; V##7 = p[224];                 \
    V##8 = p[256]; V##9 = p[288]; }

// last chunk: for sh=1 lanes, p[256]/p[288] are past end of row -> masked 0
#define LOAD10_LAST(V) {                                                        \
    const float* p = base + (15 << 9);                                          \
    V##0 = p[0];   V##1 = p[32];  V##2 = p[64];  V##3 = p[96];                  \
    V##4 = p[128]; V##5 = p[160]; V##6 = p[192]; V##7 = p[224];                 \
    V##8 = 0.f; V##9 = 0.f;                                                     \
    if (!sh) { V##8 = p[256]; V##9 = p[288]; } }

#define COMPUTE10(V) {                                                          \
    ssum += ((V##0 + V##1) + (V##2 + V##3)) + ((V##4 + V##5) + (V##6 + V##7));  \
    uint32 u0 = cvtpk(V##0, V##1), u1 = cvtpk(V##2, V##3);                      \
    uint32 u2 = cvtpk(V##4, V##5), u3 = cvtpk(V##6, V##7);                      \
    uint32 u4 = cvtpk(V##8, V##9);                                              \
    int4 a4 = make_int4((int)u0, (int)u1, (int)u2, (int)u3);                    \
    int4 b1;                                                                    \
    b1.x = (int)((u0 >> 16) | (u1 << 16));                                      \
    b1.y = (int)((u1 >> 16) | (u2 << 16));                                      \
    b1.z = (int)((u2 >> 16) | (u3 << 16));                                      \
    b1.w = (int)((u3 >> 16) | (u4 << 16));                                      \
    int4 b2 = make_int4((int)u1, (int)u2, (int)u3, (int)u4);                    \
    bf16x8 fa = __builtin_bit_cast(bf16x8, a4);                                 \
    bf16x8 f1 = __builtin_bit_cast(bf16x8, b1);                                 \
    bf16x8 f2 = __builtin_bit_cast(bf16x8, b2);                                 \
    g0 = __builtin_amdgcn_mfma_f32_32x32x16_bf16(fa, fa, g0, 0, 0, 0);          \
    g1 = __builtin_amdgcn_mfma_f32_32x32x16_bf16(fa, f1, g1, 0, 0, 0);          \
    g2 = __builtin_amdgcn_mfma_f32_32x32x16_bf16(fa, f2, g2, 0, 0, 0); }

#define ROT10(D, S) { D##0 = S##0; D##1 = S##1; D##2 = S##2; D##3 = S##3;       \
                      D##4 = S##4; D##5 = S##5; D##6 = S##6; D##7 = S##7;       \
                      D##8 = S##8; D##9 = S##9; }

__global__ __launch_bounds__(WPB * 64, 4)
void autocorr_kernel(const float* __restrict__ X, float* __restrict__ out, int nrows) {
  __shared__ short gb_all[WPB * GB_SHORTS];
  const int wave = threadIdx.x >> 6;
  const int lane = threadIdx.x & 63;
  const int row = blockIdx.x * WPB + wave;
  if (row >= nrows) return;               // no barriers anywhere: waves independent
  short* gb = gb_all + wave * GB_SHORTS;

  const int m = lane & 31;                // A-role row m / B-role col n
  const int sh = lane >> 5;               // K-half s
  const float* __restrict__ base = X + (size_t)row * T_LEN + (sh << 8) + m;

  f32x16 g0 = {}, g1 = {}, g2 = {};
  float ssum = 0.f;

  // ---- depth-2 software pipeline: A = batch c, B = batch c+1 ----
  DECL10(A) DECL10(B)
  LOAD10(A, 0)
  LOAD10(B, 1)

#pragma unroll
  for (int c = 0; c < 16; ++c) {
    DECL10(N)
    N0 = N1 = N2 = N3 = N4 = N5 = N6 = N7 = N8 = N9 = 0.f;
    if (c + 2 < 15)       LOAD10(N, c + 2)       // issue 2 iterations ahead
    else if (c + 2 == 15) LOAD10_LAST(N)
    COMPUTE10(A)                                 // waits only for batch c
    ROT10(A, B)                                  // pure renaming under unroll
    ROT10(B, N)
  }

  for (int d = 32; d > 0; d >>= 1) ssum += __shfl_xor(ssum, d, 64);

  // ---- dump G to LDS in bf16 (6.5 KB/wave) ----
#pragma unroll
  for (int v = 0; v < 16; ++v) {
    int rm = (v & 3) + (sh << 2) + ((v >> 2) << 3); // C/D row; col = m
    gb[(rm)      * GB_STRIDE + m] = f2bf(g0[v]);
    gb[(32 + rm) * GB_STRIDE + m] = f2bf(g1[v]);
    gb[(64 + rm) * GB_STRIDE + m] = f2bf(g2[v]);
  }

  // ---- diagonal-band sums: lane handles lag k = lane+1 ----
  int k = lane + 1;
  int s2 = k & 31, q = k >> 5;
  float ck = 0.f;
#pragma unroll 4
  for (int mm = 0; mm < 32; ++mm) {
    int ms = mm + s2;
    int dd = q + (ms >> 5);
    ck += bf2f(gb[(dd * 32 + mm) * GB_STRIDE + (ms & 31)]);
  }
  float c0 = 0.f;
#pragma unroll 4
  for (int mm = 0; mm < 32; ++mm) c0 += bf2f(gb[mm * GB_STRIDE + mm]); // broadcast

  // ---- centering correction: prefix (P_k) / suffix (Q_k) scans over lanes ----
  float P = X[(size_t)row * T_LEN + lane];
  float Q = X[(size_t)row * T_LEN + (T_LEN - 1 - lane)];
  for (int d = 1; d < 64; d <<= 1) {
    float tp = __shfl_up(P, (unsigned)d, 64);
    float tq = __shfl_up(Q, (unsigned)d, 64);
    if (lane >= d) { P += tp; Q += tq; }
  }
  float mu = ssum * (1.0f / (float)T_LEN);
  float Ck = ck - mu * (2.f * ssum - P - Q) + (float)(T_LEN - k) * mu * mu;
  float C0 = c0 - mu * 2.f * ssum + (float)T_LEN * mu * mu;
  out[(size_t)row * 64 + lane] = Ck / C0;
}

extern "C" void kernel_launch(void* const* d_in, const int* in_sizes, int n_in,
                              void* d_out, int out_size, void* d_ws, size_t ws_size,
                              hipStream_t stream) {
  const float* X = (const float*)d_in[0];
  float* out = (float*)d_out;
  int nrows = in_sizes[0] / T_LEN;  // 4096
  dim3 grid((nrows + WPB - 1) / WPB);
  autocorr_kernel<<<grid, dim3(WPB * 64), 0, stream>>>(X, out, nrows);
}

// Round 3
// 201.197 us; speedup vs baseline: 1.0599x; 1.0599x over previous
//
#include <hip/hip_runtime.h>

// Batched autocorrelation, X:[4096,8192] f32 -> out:[4096,64] f32.
// Per-row correlation as bf16 MFMA Gram matrices:
//   X_i[m] = x[32 i + m];  G_d[m][n] = sum_i X_i[m] * X_{i+d}[n], d=0..2
//   R_{32q+s} = sum_{m+s<32} G_q[m][m+s] + sum_{m+s>=32} G_{q+1}[m][m+s-32]
// Centering folded in algebraically (fp32):
//   C_k = R_k - mu*(2S - P_k - Q_k) + (T-k) mu^2 ;  out = C_k / C_0
//
// R5: R4's depth-2 register pipeline, SPILL-FREE.
//   R4 post-mortem: __launch_bounds__(256,4) caps the unified VGPR+AGPR file
//   at 128/wave; pipeline needs ~150 (48 acc + 30 pipeline + addressing) ->
//   ~64 MB scratch writes (WRITE_SIZE 65 MB vs 1 MB output), dur 213 µs.
//   Fix: min-waves 4 -> 3 (cap ~170). Occupancy 16 -> 12 waves/CU, but
//   per-wave loads-in-flight 10 -> 20: net outstanding bytes +50%.
//   * batch c's 10 loads issue TWO iterations before their compute.
//   * e8/e9 are direct loads (L1/L2 hits, proven free in R3) so compute(c)
//     depends ONLY on batch c -- no cross-iteration shuffle.
//   * cvt_pk_bf16_f32 (1 instr, RNE; bit-matched software pack in R3).
// LDS is only a 6.5 KB/wave bf16 G-dump for the diagonal-band reduction.

typedef __bf16 bf16x8 __attribute__((ext_vector_type(8)));
typedef float f32x16 __attribute__((ext_vector_type(16)));
typedef unsigned int uint32;

#define T_LEN 8192
#define WPB 4                       // waves (rows) per block
#define GB_STRIDE 34                // shorts per G row (+2 pad)
#define GB_SHORTS (96 * GB_STRIDE)  // 3 matrices x 32 rows = 6528 B / wave

__device__ __forceinline__ uint32 cvtpk(float lo, float hi) { // (lo, hi) RNE
  uint32 r;
  asm("v_cvt_pk_bf16_f32 %0, %1, %2" : "=v"(r) : "v"(lo), "v"(hi));
  return r;
}
__device__ __forceinline__ short f2bf(float f) {
  uint32 u = __builtin_bit_cast(uint32, f);
  return (short)((u + 0x7fffu + ((u >> 16) & 1u)) >> 16);
}
__device__ __forceinline__ float bf2f(short h) {
  uint32 u = ((uint32)(unsigned short)h) << 16;
  return __builtin_bit_cast(float, u);
}

// ---- 10-element batch macros (named regs only: no runtime indexing)
#define DECL10(V) float V##0, V##1, V##2, V##3, V##4, V##5, V##6, V##7, V##8, V##9;

// full batch: e8/e9 (p[256],p[288]) duplicate neighboring data -> L1/L2 hits,
// but keep compute(c) dependent only on batch c.
#define LOAD10(V, c) {                                                          \
    const float* p = base + ((c) << 9);                                         \
    V##0 = p[0];   V##1 = p[32];  V##2 = p[64];  V##3 = p[96];                  \
    V##4 = p[128]; V##5 = p[160]; V##6 = p[192]; V##7 = p[224];                 \
    V##8 = p[256]; V##9 = p[288]; }

// last chunk: for sh=1 lanes, p[256]/p[288] are past end of row -> masked 0
#define LOAD10_LAST(V) {                                                        \
    const float* p = base + (15 << 9);                                          \
    V##0 = p[0];   V##1 = p[32];  V##2 = p[64];  V##3 = p[96];                  \
    V##4 = p[128]; V##5 = p[160]; V##6 = p[192]; V##7 = p[224];                 \
    V##8 = 0.f; V##9 = 0.f;                                                     \
    if (!sh) { V##8 = p[256]; V##9 = p[288]; } }

#define COMPUTE10(V) {                                                          \
    ssum += ((V##0 + V##1) + (V##2 + V##3)) + ((V##4 + V##5) + (V##6 + V##7));  \
    uint32 u0 = cvtpk(V##0, V##1), u1 = cvtpk(V##2, V##3);                      \
    uint32 u2 = cvtpk(V##4, V##5), u3 = cvtpk(V##6, V##7);                      \
    uint32 u4 = cvtpk(V##8, V##9);                                              \
    int4 a4 = make_int4((int)u0, (int)u1, (int)u2, (int)u3);                    \
    int4 b1;                                                                    \
    b1.x = (int)((u0 >> 16) | (u1 << 16));                                      \
    b1.y = (int)((u1 >> 16) | (u2 << 16));                                      \
    b1.z = (int)((u2 >> 16) | (u3 << 16));                                      \
    b1.w = (int)((u3 >> 16) | (u4 << 16));                                      \
    int4 b2 = make_int4((int)u1, (int)u2, (int)u3, (int)u4);                    \
    bf16x8 fa = __builtin_bit_cast(bf16x8, a4);                                 \
    bf16x8 f1 = __builtin_bit_cast(bf16x8, b1);                                 \
    bf16x8 f2 = __builtin_bit_cast(bf16x8, b2);                                 \
    g0 = __builtin_amdgcn_mfma_f32_32x32x16_bf16(fa, fa, g0, 0, 0, 0);          \
    g1 = __builtin_amdgcn_mfma_f32_32x32x16_bf16(fa, f1, g1, 0, 0, 0);          \
    g2 = __builtin_amdgcn_mfma_f32_32x32x16_bf16(fa, f2, g2, 0, 0, 0); }

#define ROT10(D, S) { D##0 = S##0; D##1 = S##1; D##2 = S##2; D##3 = S##3;       \
                      D##4 = S##4; D##5 = S##5; D##6 = S##6; D##7 = S##7;       \
                      D##8 = S##8; D##9 = S##9; }

__global__ __launch_bounds__(WPB * 64, 3)   // cap ~170 regs: pipeline fits, NO spill
void autocorr_kernel(const float* __restrict__ X, float* __restrict__ out, int nrows) {
  __shared__ short gb_all[WPB * GB_SHORTS];
  const int wave = threadIdx.x >> 6;
  const int lane = threadIdx.x & 63;
  const int row = blockIdx.x * WPB + wave;
  if (row >= nrows) return;               // no barriers anywhere: waves independent
  short* gb = gb_all + wave * GB_SHORTS;

  const int m = lane & 31;                // A-role row m / B-role col n
  const int sh = lane >> 5;               // K-half s
  const float* __restrict__ base = X + (size_t)row * T_LEN + (sh << 8) + m;

  f32x16 g0 = {}, g1 = {}, g2 = {};
  float ssum = 0.f;

  // ---- depth-2 software pipeline: A = batch c, B = batch c+1 ----
  DECL10(A) DECL10(B)
  LOAD10(A, 0)
  LOAD10(B, 1)

#pragma unroll
  for (int c = 0; c < 16; ++c) {
    DECL10(N)
    N0 = N1 = N2 = N3 = N4 = N5 = N6 = N7 = N8 = N9 = 0.f;
    if (c + 2 < 15)       LOAD10(N, c + 2)       // issue 2 iterations ahead
    else if (c + 2 == 15) LOAD10_LAST(N)
    COMPUTE10(A)                                 // waits only for batch c
    ROT10(A, B)                                  // pure renaming under unroll
    ROT10(B, N)
  }

  for (int d = 32; d > 0; d >>= 1) ssum += __shfl_xor(ssum, d, 64);

  // ---- dump G to LDS in bf16 (6.5 KB/wave) ----
#pragma unroll
  for (int v = 0; v < 16; ++v) {
    int rm = (v & 3) + (sh << 2) + ((v >> 2) << 3); // C/D row; col = m
    gb[(rm)      * GB_STRIDE + m] = f2bf(g0[v]);
    gb[(32 + rm) * GB_STRIDE + m] = f2bf(g1[v]);
    gb[(64 + rm) * GB_STRIDE + m] = f2bf(g2[v]);
  }

  // ---- diagonal-band sums: lane handles lag k = lane+1 ----
  int k = lane + 1;
  int s2 = k & 31, q = k >> 5;
  float ck = 0.f;
#pragma unroll 4
  for (int mm = 0; mm < 32; ++mm) {
    int ms = mm + s2;
    int dd = q + (ms >> 5);
    ck += bf2f(gb[(dd * 32 + mm) * GB_STRIDE + (ms & 31)]);
  }
  float c0 = 0.f;
#pragma unroll 4
  for (int mm = 0; mm < 32; ++mm) c0 += bf2f(gb[mm * GB_STRIDE + mm]); // broadcast

  // ---- centering correction: prefix (P_k) / suffix (Q_k) scans over lanes ----
  float P = X[(size_t)row * T_LEN + lane];
  float Q = X[(size_t)row * T_LEN + (T_LEN - 1 - lane)];
  for (int d = 1; d < 64; d <<= 1) {
    float tp = __shfl_up(P, (unsigned)d, 64);
    float tq = __shfl_up(Q, (unsigned)d, 64);
    if (lane >= d) { P += tp; Q += tq; }
  }
  float mu = ssum * (1.0f / (float)T_LEN);
  float Ck = ck - mu * (2.f * ssum - P - Q) + (float)(T_LEN - k) * mu * mu;
  float C0 = c0 - mu * 2.f * ssum + (float)T_LEN * mu * mu;
  out[(size_t)row * 64 + lane] = Ck / C0;
}

extern "C" void kernel_launch(void* const* d_in, const int* in_sizes, int n_in,
                              void* d_out, int out_size, void* d_ws, size_t ws_size,
                              hipStream_t stream) {
  const float* X = (const float*)d_in[0];
  float* out = (float*)d_out;
  int nrows = in_sizes[0] / T_LEN;  // 4096
  dim3 grid((nrows + WPB - 1) / WPB);
  autocorr_kernel<<<grid, dim3(WPB * 64), 0, stream>>>(X, out, nrows);
}

// Round 4
// 190.151 us; speedup vs baseline: 1.1215x; 1.0581x over previous
//
#include <hip/hip_runtime.h>

// Batched autocorrelation, X:[4096,8192] f32 -> out:[4096,64] f32.
// R6: occupancy is GRID-capped at 16 waves/CU with 1 wave/row (4096 waves).
// R5 proved throughput ~ resident waves (16->12 waves = +33% time), so:
//   * 16x16x32 MFMA formulation: G_d (d=0..4) are 16x16 Gram matrices,
//       X_i[m] = x[16 i + m];  G_d[m][n] = sum_i X_i[m] * X_{i+d}[n]
//       C_{16q+s} = sum_mm G_{q+((mm+s)>=16)}[mm][(mm+s)&15]   (k=64 -> G4 diag)
//     -> accumulators 48 -> 20 regs.
//   * Each row split across 2 waves (half-rows i in [0,256)/[256,512)); i-ranges
//     disjoint so partial G's sum exactly; h=0's chunk-7 extras read into h=1's
//     region (in-bounds). Partials dumped bf16 to LDS, combined after one barrier.
//   * __launch_bounds__(256,8): force <=64 total regs -> 8 waves/SIMD.
//   Grid: 2048 blocks x 4 waves = 8192 waves = 32 waves/CU (2x R3).
// Centering folded in algebraically (fp32), as before:
//   C_k = R_k - mu*(2S - P_k - Q_k) + (T-k) mu^2 ;  out = C_k / C_0

typedef __bf16 bf16x8 __attribute__((ext_vector_type(8)));
typedef float f32x4 __attribute__((ext_vector_type(4)));
typedef unsigned int uint32;

#define T_LEN 8192
#define GST 18                        // shorts per G row (16 + 2 pad)
#define GB_SHORTS (80 * GST)          // 5 16x16 bf16 matrices per (row,half)

__device__ __forceinline__ uint32 cvtpk(float lo, float hi) { // (lo, hi) RNE
  uint32 r;
  asm("v_cvt_pk_bf16_f32 %0, %1, %2" : "=v"(r) : "v"(lo), "v"(hi));
  return r;
}
__device__ __forceinline__ short f2bf(float f) {
  uint32 u = __builtin_bit_cast(uint32, f);
  return (short)((u + 0x7fffu + ((u >> 16) & 1u)) >> 16);
}
__device__ __forceinline__ float bf2f(short h) {
  uint32 u = ((uint32)(unsigned short)h) << 16;
  return __builtin_bit_cast(float, u);
}

__global__ __launch_bounds__(256, 8)   // force <=64 total regs: 8 waves/SIMD
void autocorr_kernel(const float* __restrict__ X, float* __restrict__ out, int nrows) {
  __shared__ short gb_all[4 * GB_SHORTS];   // 11.5 KB/block
  __shared__ float ss[4];
  const int wv = threadIdx.x >> 6;
  const int lane = threadIdx.x & 63;
  const int pr = wv >> 1;             // row-pair slot within block (0,1)
  const int h  = wv & 1;              // which half of the row this wave owns
  const int row = blockIdx.x * 2 + pr;
  const int rowc = row < nrows ? row : 0;   // clamp reads; tail rows don't write

  short* gme = gb_all + wv * GB_SHORTS;

  const int m  = lane & 15;           // A row / B col
  const int lg = lane >> 4;           // K quarter: k = 8*lg + j
  const float* __restrict__ base =
      X + (size_t)rowc * T_LEN + (h << 12) + (lg << 7) + m;

  f32x4 g0 = {}, g1 = {}, g2 = {}, g3 = {}, g4 = {};
  float ssum = 0.f;

  // element j of A-frag, chunk c: x[row, h*4096 + 512c + 128*lg + 16*j + m]
  // B_d frag j = element (j+d): j+d<8 from A data; j+d>=8 from extras e8..e11.
#define BODY()                                                                 \
  {                                                                            \
    ssum += ((e0 + e1) + (e2 + e3)) + ((e4 + e5) + (e6 + e7));                 \
    uint32 u0 = cvtpk(e0, e1), u1 = cvtpk(e2, e3), u2 = cvtpk(e4, e5);         \
    uint32 u3 = cvtpk(e6, e7), u4 = cvtpk(e8, e9), u5 = cvtpk(e10, e11);       \
    uint32 a01 = (u0 >> 16) | (u1 << 16), a12 = (u1 >> 16) | (u2 << 16);       \
    uint32 a23 = (u2 >> 16) | (u3 << 16), a34 = (u3 >> 16) | (u4 << 16);       \
    uint32 a45 = (u4 >> 16) | (u5 << 16);                                      \
    int4 A4 = make_int4((int)u0, (int)u1, (int)u2, (int)u3);                   \
    int4 C1 = make_int4((int)a01, (int)a12, (int)a23, (int)a34);               \
    int4 C2 = make_int4((int)u1, (int)u2, (int)u3, (int)u4);                   \
    int4 C3 = make_int4((int)a12, (int)a23, (int)a34, (int)a45);               \
    int4 C4 = make_int4((int)u2, (int)u3, (int)u4, (int)u5);                   \
    bf16x8 fa = __builtin_bit_cast(bf16x8, A4);                                \
    bf16x8 f1 = __builtin_bit_cast(bf16x8, C1);                                \
    bf16x8 f2 = __builtin_bit_cast(bf16x8, C2);                                \
    bf16x8 f3 = __builtin_bit_cast(bf16x8, C3);                                \
    bf16x8 f4 = __builtin_bit_cast(bf16x8, C4);                                \
    g0 = __builtin_amdgcn_mfma_f32_16x16x32_bf16(fa, fa, g0, 0, 0, 0);         \
    g1 = __builtin_amdgcn_mfma_f32_16x16x32_bf16(fa, f1, g1, 0, 0, 0);         \
    g2 = __builtin_amdgcn_mfma_f32_16x16x32_bf16(fa, f2, g2, 0, 0, 0);         \
    g3 = __builtin_amdgcn_mfma_f32_16x16x32_bf16(fa, f3, g3, 0, 0, 0);         \
    g4 = __builtin_amdgcn_mfma_f32_16x16x32_bf16(fa, f4, g4, 0, 0, 0);         \
  }

#pragma unroll 1                       // small loop: TLP (32 waves/CU) hides latency
  for (int c = 0; c < 7; ++c) {
    const float* p = base + (c << 9);
    float e0 = p[0],   e1 = p[16],  e2 = p[32],   e3 = p[48];
    float e4 = p[64],  e5 = p[80],  e6 = p[96],   e7 = p[112];
    float e8 = p[128], e9 = p[144], e10 = p[160], e11 = p[176];
    BODY()
  }
  { // local chunk 7: only (h==1, lg==3) extras are past end of row -> 0
    const float* p = base + (7 << 9);
    float e0 = p[0],  e1 = p[16], e2 = p[32],  e3 = p[48];
    float e4 = p[64], e5 = p[80], e6 = p[96],  e7 = p[112];
    float e8 = 0.f, e9 = 0.f, e10 = 0.f, e11 = 0.f;
    if (!(h && lg == 3)) { e8 = p[128]; e9 = p[144]; e10 = p[160]; e11 = p[176]; }
    BODY()
  }
#undef BODY

  for (int d = 32; d > 0; d >>= 1) ssum += __shfl_xor(ssum, d, 64);

  // ---- dump partial G to LDS in bf16 (C/D layout: col=lane&15, row=lg*4+v) ----
#pragma unroll
  for (int v = 0; v < 4; ++v) {
    int rm = (lg << 2) + v;
    gme[(rm)      * GST + m] = f2bf(g0[v]);
    gme[(16 + rm) * GST + m] = f2bf(g1[v]);
    gme[(32 + rm) * GST + m] = f2bf(g2[v]);
    gme[(48 + rm) * GST + m] = f2bf(g3[v]);
    gme[(64 + rm) * GST + m] = f2bf(g4[v]);
  }
  if (lane == 0) ss[wv] = ssum;
  __syncthreads();

  if (h == 0 && row < nrows) {
    const short* ga = gb_all + (pr * 2) * GB_SHORTS;  // this row, half 0
    const short* gh = ga + GB_SHORTS;                 // this row, half 1
    float S = ss[pr * 2] + ss[pr * 2 + 1];

    // ---- diagonal-band sums: lane handles lag k = lane+1 (1..64) ----
    int k = lane + 1;
    int s2 = k & 15, q = k >> 4;
    float ck = 0.f;
#pragma unroll 4
    for (int mm = 0; mm < 16; ++mm) {
      int ms = mm + s2;
      int idx = ((q + (ms >> 4)) * 16 + mm) * GST + (ms & 15);
      ck += bf2f(ga[idx]) + bf2f(gh[idx]);
    }
    float c0 = 0.f;
#pragma unroll 4
    for (int mm = 0; mm < 16; ++mm)
      c0 += bf2f(ga[mm * GST + mm]) + bf2f(gh[mm * GST + mm]);

    // ---- centering correction: prefix (P_k) / suffix (Q_k) scans over lanes ----
    float P = X[(size_t)row * T_LEN + lane];
    float Q = X[(size_t)row * T_LEN + (T_LEN - 1 - lane)];
    for (int d = 1; d < 64; d <<= 1) {
      float tp = __shfl_up(P, (unsigned)d, 64);
      float tq = __shfl_up(Q, (unsigned)d, 64);
      if (lane >= d) { P += tp; Q += tq; }
    }
    float mu = S * (1.0f / (float)T_LEN);
    float Ck = ck - mu * (2.f * S - P - Q) + (float)(T_LEN - k) * mu * mu;
    float C0 = c0 - mu * 2.f * S + (float)T_LEN * mu * mu;
    out[(size_t)row * 64 + lane] = Ck / C0;
  }
}

extern "C" void kernel_launch(void* const* d_in, const int* in_sizes, int n_in,
                              void* d_out, int out_size, void* d_ws, size_t ws_size,
                              hipStream_t stream) {
  const float* X = (const float*)d_in[0];
  float* out = (float*)d_out;
  int nrows = in_sizes[0] / T_LEN;  // 4096
  dim3 grid((nrows + 1) / 2);       // 2 rows per block, 2 waves per row
  autocorr_kernel<<<grid, dim3(256), 0, stream>>>(X, out, nrows);
}